// Round 2
// baseline (129.977 us; speedup 1.0000x reference)
//
#include <hip/hip_runtime.h>

#define NB 8
#define NS 4096
#define ND 1280
#define NR 64
#define EW 6656   // D + R*R + D

typedef __attribute__((ext_vector_type(4))) float f4;
typedef __attribute__((ext_vector_type(8))) short bf8;

__device__ __forceinline__ unsigned short f2bf(float f) {
  union { float f; unsigned u; } v; v.f = f;
  unsigned u = v.u + 0x7FFFu + ((v.u >> 16) & 1u);  // RNE
  return (unsigned short)(u >> 16);
}

// ---------------- P1: W2F (bf16, MFMA-fragment-ordered) ----------------
// W2[b,q,d] = down_w[b,d] * sum_r mid[b,q,r] * w_down[r,d]
// frag layout: index = ((b*40 + kt)*4 + nt)*512 + lane*8 + j
//   kt = d/32, nt = q/16, lane = ((d%32)/8)*16 + (q%16), j = d%8
__global__ __launch_bounds__(256) void prep_w2(const float* __restrict__ embed,
                                               const float* __restrict__ w_down,
                                               unsigned short* __restrict__ W2F) {
  const int blk = blockIdx.x;           // b*20 + qg*5 + dg
  const int b  = blk / 20;
  const int qg = (blk % 20) / 5;
  const int dg = blk % 5;
  const int t  = threadIdx.x;
  __shared__ float mids[16][64];
  #pragma unroll
  for (int i = 0; i < 4; ++i) {
    int idx = t + i * 256;
    mids[idx >> 6][idx & 63] = embed[b * EW + ND + qg * 1024 + idx];
  }
  __syncthreads();
  const int d = dg * 256 + t;
  float acc[16];
  #pragma unroll
  for (int q = 0; q < 16; ++q) acc[q] = 0.f;
  for (int r = 0; r < 64; ++r) {
    float wd = w_down[r * ND + d];
    #pragma unroll
    for (int q = 0; q < 16; ++q) acc[q] += mids[q][r] * wd;
  }
  const float dwn = embed[b * EW + d];
  const int kt = d >> 5, lanehi = (d & 31) >> 3, jj = d & 7;
  #pragma unroll
  for (int q = 0; q < 16; ++q)
    W2F[(((b * 40 + kt) * 4 + qg) << 9) + (lanehi * 16 + q) * 8 + jj] = f2bf(acc[q] * dwn);
}

// ---------------- P2: W3F (w_up, bf16 frag-ordered) + h2 bias ----------------
// W3F index = ((kt*80 + nt)*64 + lane)*8 + j ; kt=q/32, nt=d/16, lane=((q%32)/8)*16 + d%16, j=q%8
__global__ __launch_bounds__(256) void prep_w3(const float* __restrict__ w_up,
                                               const float* __restrict__ b_down,
                                               const float* __restrict__ embed,
                                               unsigned short* __restrict__ W3F,
                                               float* __restrict__ h2bias) {
  if (blockIdx.x < 320) {
    int g = blockIdx.x * 256 + threadIdx.x;   // g = d*64 + q
    int d = g >> 6, q = g & 63;
    int kt = q >> 5, nt = d >> 4, lanei = ((q & 31) >> 3) * 16 + (d & 15), jj = q & 7;
    W3F[((kt * 80 + nt) * 64 + lanei) * 8 + jj] = f2bf(w_up[g]);
  } else {
    #pragma unroll
    for (int ii = 0; ii < 2; ++ii) {
      int id = ii * 256 + threadIdx.x;        // id = b*64 + q
      int bb = id >> 6, q = id & 63;
      float s = 0.f;
      for (int r = 0; r < 64; ++r) s += b_down[r] * embed[bb * EW + ND + q * 64 + r];
      h2bias[id] = s;
    }
  }
}

// ---------------- main fused kernel ----------------
// Per block: 64 rows of one batch. Per wave: 16 rows (wave-exclusive).
// Stage 1: h2[16x64] = x_rows @ W2[b]^T   (K=1280, direct global->reg A-frags)
// Stage 2: out[16x1280] = (h2 @ w_up^T + b_up) * up_w  -- EACH WAVE DOES ALL 80 d-tiles
__global__ __launch_bounds__(256) void fused_main(const float* __restrict__ x,
                                                  const float* __restrict__ embed,
                                                  const float* __restrict__ b_up,
                                                  const unsigned short* __restrict__ W2F,
                                                  const unsigned short* __restrict__ W3F,
                                                  const float* __restrict__ h2bias,
                                                  float* __restrict__ out) {
  const int tid  = threadIdx.x;
  const int lane = tid & 63;
  const int w    = tid >> 6;
  const int b    = blockIdx.x & 7;        // batch -> XCD round-robin (L2 locality for W2F[b])
  const int tile = blockIdx.x >> 3;
  const int lo16 = lane & 15;
  const int hi4  = lane >> 4;
  const int wrow = tile * 64 + w * 16;    // this wave's first global row

  __shared__ __align__(16) unsigned short h2s[64][72]; // padded: <=2-way bank aliasing

  f4 acc[4] = {};
  // A-operand: this lane supplies x row (wrow + lo16), k = hi4*8 + j (per 32-wide K block)
  const float* xrow = x + ((size_t)b * NS + wrow + lo16) * ND;
  const unsigned short* w2b = W2F + (size_t)b * 81920;  // b*40*4*512

  // ---- stage 1: K = 1280 in 20 chunks of 64
  for (int ck = 0; ck < 20; ++ck) {
    const float* xp = xrow + ck * 64 + hi4 * 8;
    f4 a00 = *(const f4*)(xp);
    f4 a01 = *(const f4*)(xp + 4);
    f4 a10 = *(const f4*)(xp + 32);
    f4 a11 = *(const f4*)(xp + 36);
    bf8 bfr[2][4];
    #pragma unroll
    for (int kb = 0; kb < 2; ++kb) {
      #pragma unroll
      for (int nt = 0; nt < 4; ++nt)
        bfr[kb][nt] = *(const bf8*)(w2b + ((((ck * 2 + kb) * 4 + nt) << 9) + lane * 8));
    }
    bf8 af0, af1;
    #pragma unroll
    for (int j = 0; j < 4; ++j) {
      af0[j]     = (short)f2bf(a00[j]);
      af0[4 + j] = (short)f2bf(a01[j]);
      af1[j]     = (short)f2bf(a10[j]);
      af1[4 + j] = (short)f2bf(a11[j]);
    }
    #pragma unroll
    for (int nt = 0; nt < 4; ++nt)
      acc[nt] = __builtin_amdgcn_mfma_f32_16x16x32_bf16(af0, bfr[0][nt], acc[nt], 0, 0, 0);
    #pragma unroll
    for (int nt = 0; nt < 4; ++nt)
      acc[nt] = __builtin_amdgcn_mfma_f32_16x16x32_bf16(af1, bfr[1][nt], acc[nt], 0, 0, 0);
  }

  // ---- h2 -> LDS as bf16 (+ b_down@mid bias). C/D: col=lane&15, row=(lane>>4)*4+reg
  {
    const float* bp = h2bias + b * 64;
    #pragma unroll
    for (int nt = 0; nt < 4; ++nt) {
      int q = nt * 16 + lo16;
      float bq = bp[q];
      #pragma unroll
      for (int j = 0; j < 4; ++j)
        h2s[w * 16 + hi4 * 4 + j][q] = f2bf(acc[nt][j] + bq);
    }
  }
  __syncthreads();

  // ---- stage 2: out rows = this wave's 16; loop over ALL 80 d-tiles
  bf8 ha0 = *(const bf8*)&h2s[w * 16 + lo16][hi4 * 8];        // q = 0..31 slice
  bf8 ha1 = *(const bf8*)&h2s[w * 16 + lo16][32 + hi4 * 8];   // q = 32..63 slice
  const float* upw = embed + b * EW + (EW - ND);
  float* outp = out + (size_t)(b * NS + wrow + hi4 * 4) * ND;

  for (int dt = 0; dt < 80; ++dt) {
    bf8 b0 = *(const bf8*)(W3F + (size_t)(dt * 64 + lane) * 8);
    bf8 b1 = *(const bf8*)(W3F + (size_t)((80 + dt) * 64 + lane) * 8);
    f4 o = {};
    o = __builtin_amdgcn_mfma_f32_16x16x32_bf16(ha0, b0, o, 0, 0, 0);
    o = __builtin_amdgcn_mfma_f32_16x16x32_bf16(ha1, b1, o, 0, 0, 0);
    int d = dt * 16 + lo16;
    float scale = upw[d];
    float bu = b_up[d];
    #pragma unroll
    for (int j = 0; j < 4; ++j)
      outp[(size_t)j * ND + d] = (o[j] + bu) * scale;
  }
}

extern "C" void kernel_launch(void* const* d_in, const int* in_sizes, int n_in,
                              void* d_out, int out_size, void* d_ws, size_t ws_size,
                              hipStream_t stream) {
  const float* x      = (const float*)d_in[0];
  const float* embed  = (const float*)d_in[1];
  const float* w_down = (const float*)d_in[2];
  const float* b_down = (const float*)d_in[3];
  const float* w_up   = (const float*)d_in[4];
  const float* b_up   = (const float*)d_in[5];
  float* out = (float*)d_out;

  unsigned short* W2F = (unsigned short*)d_ws;            // 655360 elems (1.31 MB)
  unsigned short* W3F = W2F + 8 * 40 * 4 * 512;           // 81920 elems (164 KB)
  float* h2bias = (float*)(W3F + 2 * 80 * 64 * 8);        // 512 floats

  prep_w2<<<160, 256, 0, stream>>>(embed, w_down, W2F);
  prep_w3<<<321, 256, 0, stream>>>(w_up, b_down, embed, W3F, h2bias);
  fused_main<<<512, 256, 0, stream>>>(x, embed, b_up, W2F, W3F, h2bias, out);
}

// Round 3
// 128.667 us; speedup vs baseline: 1.0102x; 1.0102x over previous
//
#include <hip/hip_runtime.h>

#define NB 8
#define NS 4096
#define ND 1280
#define NR 64
#define EW 6656   // D + R*R + D

typedef __attribute__((ext_vector_type(4))) float f4;
typedef __attribute__((ext_vector_type(8))) short bf8;

__device__ __forceinline__ unsigned short f2bf(float f) {
  union { float f; unsigned u; } v; v.f = f;
  unsigned u = v.u + 0x7FFFu + ((v.u >> 16) & 1u);  // RNE
  return (unsigned short)(u >> 16);
}

// ---------------- prep (merged): W2F, W3F, h2bias ----------------
// W2F frag layout: index = ((b*40 + kt)*4 + nt)*512 + lane*8 + j
//   kt = d/32, nt = q/16, lane = ((d%32)/8)*16 + (q%16), j = d%8
// W3F index = ((kt*80 + nt)*64 + lane)*8 + j ; kt=q/32, nt=d/16,
//   lane=((q%32)/8)*16 + d%16, j=q%8
__global__ __launch_bounds__(256) void prep_all(const float* __restrict__ embed,
                                                const float* __restrict__ w_down,
                                                const float* __restrict__ w_up,
                                                const float* __restrict__ b_down,
                                                unsigned short* __restrict__ W2F,
                                                unsigned short* __restrict__ W3F,
                                                float* __restrict__ h2bias) {
  const int blk = blockIdx.x;
  const int t   = threadIdx.x;
  if (blk < 160) {
    // W2[b,q,d] = down_w[b,d] * sum_r mid[b,q,r] * w_down[r,d]
    const int b  = blk / 20;
    const int qg = (blk % 20) / 5;
    const int dg = blk % 5;
    __shared__ float mids[16][64];
    #pragma unroll
    for (int i = 0; i < 4; ++i) {
      int idx = t + i * 256;
      mids[idx >> 6][idx & 63] = embed[b * EW + ND + qg * 1024 + idx];
    }
    __syncthreads();
    const int d = dg * 256 + t;
    float acc[16];
    #pragma unroll
    for (int q = 0; q < 16; ++q) acc[q] = 0.f;
    for (int r = 0; r < 64; r += 8) {
      float wd[8];
      #pragma unroll
      for (int u = 0; u < 8; ++u) wd[u] = w_down[(r + u) * ND + d];
      #pragma unroll
      for (int u = 0; u < 8; ++u)
        #pragma unroll
        for (int q = 0; q < 16; ++q) acc[q] += mids[q][r + u] * wd[u];
    }
    const float dwn = embed[b * EW + d];
    const int kt = d >> 5, lanehi = (d & 31) >> 3, jj = d & 7;
    #pragma unroll
    for (int q = 0; q < 16; ++q)
      W2F[(((b * 40 + kt) * 4 + qg) << 9) + (lanehi * 16 + q) * 8 + jj] = f2bf(acc[q] * dwn);
  } else if (blk < 480) {
    int g = (blk - 160) * 256 + t;            // g = d*64 + q
    int d = g >> 6, q = g & 63;
    int kt = q >> 5, nt = d >> 4, lanei = ((q & 31) >> 3) * 16 + (d & 15), jj = q & 7;
    W3F[((kt * 80 + nt) * 64 + lanei) * 8 + jj] = f2bf(w_up[g]);
  } else {
    #pragma unroll
    for (int ii = 0; ii < 2; ++ii) {
      int id = ii * 256 + t;                  // id = b*64 + q
      int bb = id >> 6, q = id & 63;
      float s = 0.f;
      for (int r = 0; r < 64; ++r) s += b_down[r] * embed[bb * EW + ND + q * 64 + r];
      h2bias[id] = s;
    }
  }
}

// ---------------- main fused kernel ----------------
// Block: 32 rows of one batch, 4 waves = 2 row-tiles (rt) x 2 K-halves (kh).
// Stage 1: each wave computes PARTIAL h2[16x64] over its 640-wide K half.
// Combine partials (fp32) via LDS, add bias, cvt bf16 -> A-frags in regs.
// Stage 2: wave (kh,rt) does d-tiles [kh*40, kh*40+40) for row-tile rt.
__global__ __launch_bounds__(256, 4) void fused_main(const float* __restrict__ x,
                                                     const float* __restrict__ embed,
                                                     const float* __restrict__ b_up,
                                                     const unsigned short* __restrict__ W2F,
                                                     const unsigned short* __restrict__ W3F,
                                                     const float* __restrict__ h2bias,
                                                     float* __restrict__ out) {
  const int tid  = threadIdx.x;
  const int lane = tid & 63;
  const int w    = tid >> 6;
  const int kh   = w >> 1;                // K-half 0/1
  const int rt   = w & 1;                 // row-tile 0/1
  const int b    = blockIdx.x & 7;        // batch -> XCD round-robin (W2F[b] L2-resident)
  const int tile = blockIdx.x >> 3;       // 0..127
  const int lo16 = lane & 15;
  const int hi4  = lane >> 4;
  const int wrow = tile * 32 + rt * 16;

  __shared__ __align__(16) float h2p[2][2][16][68];  // [kh][rt][row][q] pad->bank-safe, 16B-aligned
  __shared__ float bias_s[64];

  if (tid < 64) bias_s[tid] = h2bias[b * 64 + tid];

  f4 acc[4] = {};
  // A-operand: lane supplies x row (wrow+lo16), k = kh*640 + ck*64 + {hi4*8+j, +32}
  const float* xrow = x + ((size_t)b * NS + wrow + lo16) * ND + kh * 640 + hi4 * 8;
  const unsigned short* w2b = W2F + (size_t)b * 81920;

  // prologue: prefetch chunk 0
  f4 a0 = *(const f4*)(xrow);
  f4 a1 = *(const f4*)(xrow + 4);
  f4 a2 = *(const f4*)(xrow + 32);
  f4 a3 = *(const f4*)(xrow + 36);

  for (int ck = 0; ck < 10; ++ck) {
    const int g = kh * 10 + ck;
    // B-frags for current chunk (L2-resident) — issued first, covered by cvt chain
    bf8 bw[8];
    const unsigned short* wp = w2b + (((g * 2) * 4) << 9) + lane * 8;
    #pragma unroll
    for (int i = 0; i < 8; ++i)
      bw[i] = *(const bf8*)(wp + (i << 9));
    // depth-1 prefetch of next x chunk (clamped on last iter; redundant L2 hit)
    const int nck = (ck < 9) ? ck + 1 : 9;
    const float* xn = xrow + nck * 64;
    f4 na0 = *(const f4*)(xn);
    f4 na1 = *(const f4*)(xn + 4);
    f4 na2 = *(const f4*)(xn + 32);
    f4 na3 = *(const f4*)(xn + 36);
    // convert current chunk + MFMA
    bf8 af0, af1;
    #pragma unroll
    for (int j = 0; j < 4; ++j) {
      af0[j]     = (short)f2bf(a0[j]);
      af0[4 + j] = (short)f2bf(a1[j]);
      af1[j]     = (short)f2bf(a2[j]);
      af1[4 + j] = (short)f2bf(a3[j]);
    }
    #pragma unroll
    for (int nt = 0; nt < 4; ++nt)
      acc[nt] = __builtin_amdgcn_mfma_f32_16x16x32_bf16(af0, bw[nt], acc[nt], 0, 0, 0);
    #pragma unroll
    for (int nt = 0; nt < 4; ++nt)
      acc[nt] = __builtin_amdgcn_mfma_f32_16x16x32_bf16(af1, bw[4 + nt], acc[nt], 0, 0, 0);
    a0 = na0; a1 = na1; a2 = na2; a3 = na3;
  }

  // ---- partial h2 -> LDS (fp32). C/D: col(q)=lane&15 + nt*16, row=(lane>>4)*4+reg
  #pragma unroll
  for (int nt = 0; nt < 4; ++nt)
    #pragma unroll
    for (int j = 0; j < 4; ++j)
      h2p[kh][rt][hi4 * 4 + j][nt * 16 + lo16] = acc[nt][j];
  __syncthreads();

  // ---- combine both K-halves + bias, build A-frags for stage 2
  const int row = lo16;
  f4 u0 = *(const f4*)&h2p[0][rt][row][hi4 * 8];
  f4 u1 = *(const f4*)&h2p[0][rt][row][hi4 * 8 + 4];
  f4 v0 = *(const f4*)&h2p[1][rt][row][hi4 * 8];
  f4 v1 = *(const f4*)&h2p[1][rt][row][hi4 * 8 + 4];
  f4 u2 = *(const f4*)&h2p[0][rt][row][32 + hi4 * 8];
  f4 u3 = *(const f4*)&h2p[0][rt][row][32 + hi4 * 8 + 4];
  f4 v2 = *(const f4*)&h2p[1][rt][row][32 + hi4 * 8];
  f4 v3 = *(const f4*)&h2p[1][rt][row][32 + hi4 * 8 + 4];
  bf8 ha0, ha1;
  #pragma unroll
  for (int j = 0; j < 4; ++j) {
    ha0[j]     = (short)f2bf(u0[j] + v0[j] + bias_s[hi4 * 8 + j]);
    ha0[4 + j] = (short)f2bf(u1[j] + v1[j] + bias_s[hi4 * 8 + 4 + j]);
    ha1[j]     = (short)f2bf(u2[j] + v2[j] + bias_s[32 + hi4 * 8 + j]);
    ha1[4 + j] = (short)f2bf(u3[j] + v3[j] + bias_s[32 + hi4 * 8 + 4 + j]);
  }

  // ---- stage 2: 40 d-tiles for this wave, depth-1 W3F prefetch
  const float* upw = embed + b * EW + (EW - ND);
  float* outp = out + ((size_t)b * NS + wrow + hi4 * 4) * ND;
  const int dt0 = kh * 40;
  bf8 b0 = *(const bf8*)(W3F + (size_t)(dt0 * 64 + lane) * 8);
  bf8 b1 = *(const bf8*)(W3F + (size_t)((80 + dt0) * 64 + lane) * 8);

  for (int i = 0; i < 40; ++i) {
    const int dt  = dt0 + i;
    const int pdt = (i < 39) ? dt + 1 : dt;
    bf8 nb0 = *(const bf8*)(W3F + (size_t)(pdt * 64 + lane) * 8);
    bf8 nb1 = *(const bf8*)(W3F + (size_t)((80 + pdt) * 64 + lane) * 8);
    f4 o = {};
    o = __builtin_amdgcn_mfma_f32_16x16x32_bf16(ha0, b0, o, 0, 0, 0);
    o = __builtin_amdgcn_mfma_f32_16x16x32_bf16(ha1, b1, o, 0, 0, 0);
    const int d = dt * 16 + lo16;
    const float scale = upw[d];
    const float bu = b_up[d];
    #pragma unroll
    for (int j = 0; j < 4; ++j)
      outp[(size_t)j * ND + d] = (o[j] + bu) * scale;
    b0 = nb0; b1 = nb1;
  }
}

extern "C" void kernel_launch(void* const* d_in, const int* in_sizes, int n_in,
                              void* d_out, int out_size, void* d_ws, size_t ws_size,
                              hipStream_t stream) {
  const float* x      = (const float*)d_in[0];
  const float* embed  = (const float*)d_in[1];
  const float* w_down = (const float*)d_in[2];
  const float* b_down = (const float*)d_in[3];
  const float* w_up   = (const float*)d_in[4];
  const float* b_up   = (const float*)d_in[5];
  float* out = (float*)d_out;

  unsigned short* W2F = (unsigned short*)d_ws;            // 655360 shorts (1.31 MB)
  unsigned short* W3F = W2F + 8 * 40 * 4 * 512;           // 81920 shorts (164 KB)
  float* h2bias = (float*)(W3F + 2 * 80 * 64 * 8);        // 512 floats

  prep_all<<<481, 256, 0, stream>>>(embed, w_down, w_up, b_down, W2F, W3F, h2bias);
  fused_main<<<1024, 256, 0, stream>>>(x, embed, b_up, W2F, W3F, h2bias, out);
}

// Round 4
// 124.005 us; speedup vs baseline: 1.0482x; 1.0376x over previous
//
#include <hip/hip_runtime.h>

#define NB 8
#define NS 4096
#define ND 1280
#define NR 64
#define EW 6656   // D + R*R + D

typedef __attribute__((ext_vector_type(4))) float f4;
typedef __attribute__((ext_vector_type(8))) short bf8;

__device__ __forceinline__ unsigned short f2bf(float f) {
  union { float f; unsigned u; } v; v.f = f;
  unsigned u = v.u + 0x7FFFu + ((v.u >> 16) & 1u);  // RNE
  return (unsigned short)(u >> 16);
}

// ---------------- prep (merged): W2F, W3F, h2bias ----------------
// W2F frag layout: index = ((b*40 + kt)*4 + nt)*512 + lane*8 + j
//   kt = d/32, nt = q/16, lane = ((d%32)/8)*16 + (q%16), j = d%8
// W3F index = ((kt*80 + nt)*64 + lane)*8 + j ; kt=q/32, nt=d/16,
//   lane=((q%32)/8)*16 + d%16, j=q%8
__global__ __launch_bounds__(256) void prep_all(const float* __restrict__ embed,
                                                const float* __restrict__ w_down,
                                                const float* __restrict__ w_up,
                                                const float* __restrict__ b_down,
                                                unsigned short* __restrict__ W2F,
                                                unsigned short* __restrict__ W3F,
                                                float* __restrict__ h2bias) {
  const int blk = blockIdx.x;
  const int t   = threadIdx.x;
  if (blk < 160) {
    const int b  = blk / 20;
    const int qg = (blk % 20) / 5;
    const int dg = blk % 5;
    __shared__ float mids[16][64];
    #pragma unroll
    for (int i = 0; i < 4; ++i) {
      int idx = t + i * 256;
      mids[idx >> 6][idx & 63] = embed[b * EW + ND + qg * 1024 + idx];
    }
    __syncthreads();
    const int d = dg * 256 + t;
    float acc[16];
    #pragma unroll
    for (int q = 0; q < 16; ++q) acc[q] = 0.f;
    for (int r = 0; r < 64; r += 8) {
      float wd[8];
      #pragma unroll
      for (int u = 0; u < 8; ++u) wd[u] = w_down[(r + u) * ND + d];
      #pragma unroll
      for (int u = 0; u < 8; ++u)
        #pragma unroll
        for (int q = 0; q < 16; ++q) acc[q] += mids[q][r + u] * wd[u];
    }
    const float dwn = embed[b * EW + d];
    const int kt = d >> 5, lanehi = (d & 31) >> 3, jj = d & 7;
    #pragma unroll
    for (int q = 0; q < 16; ++q)
      W2F[(((b * 40 + kt) * 4 + qg) << 9) + (lanehi * 16 + q) * 8 + jj] = f2bf(acc[q] * dwn);
  } else if (blk < 480) {
    int g = (blk - 160) * 256 + t;            // g = d*64 + q
    int d = g >> 6, q = g & 63;
    int kt = q >> 5, nt = d >> 4, lanei = ((q & 31) >> 3) * 16 + (d & 15), jj = q & 7;
    W3F[((kt * 80 + nt) * 64 + lanei) * 8 + jj] = f2bf(w_up[g]);
  } else {
    #pragma unroll
    for (int ii = 0; ii < 2; ++ii) {
      int id = ii * 256 + t;                  // id = b*64 + q
      int bb = id >> 6, q = id & 63;
      float s = 0.f;
      for (int r = 0; r < 64; ++r) s += b_down[r] * embed[bb * EW + ND + q * 64 + r];
      h2bias[id] = s;
    }
  }
}

// ---------------- main fused kernel ----------------
// Block: 32 rows of one batch; 4 waves = 2 row-tiles (rt) x 2 K-halves (kh).
// Stage 1: x staged global->LDS via global_load_lds (256B segments), source
//   XOR-pre-swizzled (chunk c ^= row), LDS linear, wave-private double buffer,
//   drain-then-issue vmcnt(0) loop (no barrier in K-loop).
// h2 partials combined through LDS (region aliases xs, barrier-separated).
// Stage 2: wave (kh,rt) does d-tiles [kh*40, kh*40+40) for row-tile rt.
__global__ __launch_bounds__(256, 4) void fused_main(const float* __restrict__ x,
                                                     const float* __restrict__ embed,
                                                     const float* __restrict__ b_up,
                                                     const unsigned short* __restrict__ W2F,
                                                     const unsigned short* __restrict__ W3F,
                                                     const float* __restrict__ h2bias,
                                                     float* __restrict__ out) {
  const int tid  = threadIdx.x;
  const int lane = tid & 63;
  const int w    = tid >> 6;
  const int kh   = w >> 1;                // K-half 0/1
  const int rt   = w & 1;                 // row-tile 0/1
  const int b    = blockIdx.x & 7;        // batch -> XCD round-robin (W2F[b] L2-resident)
  const int tile = blockIdx.x >> 3;       // 0..127
  const int lo16 = lane & 15;
  const int hi4  = lane >> 4;
  const int wrow = tile * 32 + rt * 16;

  // 32KB x-staging (4 waves x 2 bufs x 4KB); h2p ALIASES it (barrier-separated)
  __shared__ __align__(16) char smem[32768 + 256];
  float (*xs)[2][1024]    = (float (*)[2][1024])smem;          // [wave][buf][16rows*64cols]
  float (*h2p)[2][16][68] = (float (*)[2][16][68])smem;        // [kh][rt][row][q]
  float* bias_s           = (float*)(smem + 32768);

  if (tid < 64) bias_s[tid] = h2bias[b * 64 + tid];

  const float* xbase = x + ((size_t)b * NS + wrow) * ND + kh * 640;
  const unsigned short* w2b = W2F + (size_t)b * 81920;

  // DMA one 16x64 chunk: instr `it` covers rows it*4..it*4+3, 256B/row.
  // LDS[row][c16] = global chunk (c16 ^ row)  (involution swizzle)
  #define ISSUE_DMA(ck, buf)                                                         \
    _Pragma("unroll")                                                                \
    for (int it = 0; it < 4; ++it) {                                                 \
      const int rloc = it * 4 + hi4;                                                 \
      const int cf   = lo16 ^ rloc;                                                  \
      const float* src = xbase + (size_t)rloc * ND + (ck) * 64 + cf * 4;             \
      __builtin_amdgcn_global_load_lds((__attribute__((address_space(1))) void*)src, \
          (__attribute__((address_space(3))) void*)&xs[w][buf][it * 256], 16, 0, 0); \
    }

  f4 acc[4] = {};
  bf8 bw[8];

  // prologue: chunk 0 DMA + W2F frags for chunk 0
  ISSUE_DMA(0, 0)
  {
    const unsigned short* wp = w2b + (((kh * 10) * 8) << 9) + lane * 8;
    #pragma unroll
    for (int i = 0; i < 8; ++i) bw[i] = *(const bf8*)(wp + (i << 9));
  }

  for (int ck = 0; ck < 10; ++ck) {
    const int buf = ck & 1;
    // drain loads issued one iteration ago (DMA(ck) + bw(ck) already waited on)
    asm volatile("s_waitcnt vmcnt(0)" ::: "memory");
    const f4* xp = (const f4*)&xs[w][buf][0];
    f4 a0 = xp[lo16 * 16 + ((hi4 * 2)     ^ lo16)];
    f4 a1 = xp[lo16 * 16 + ((hi4 * 2 + 1) ^ lo16)];
    f4 a2 = xp[lo16 * 16 + ((hi4 * 2 + 8) ^ lo16)];
    f4 a3 = xp[lo16 * 16 + ((hi4 * 2 + 9) ^ lo16)];
    // issue next chunk's DMA + W2F loads (depth-1 on both streams)
    bf8 bn[8];
    const bool more = (ck < 9);
    if (more) {
      ISSUE_DMA(ck + 1, buf ^ 1)
      const unsigned short* wp = w2b + (size_t)(((kh * 10 + ck + 1) * 8) << 9) + lane * 8;
      #pragma unroll
      for (int i = 0; i < 8; ++i) bn[i] = *(const bf8*)(wp + (i << 9));
    }
    // convert + MFMA on current chunk
    bf8 af0, af1;
    #pragma unroll
    for (int j = 0; j < 4; ++j) {
      af0[j]     = (short)f2bf(a0[j]);
      af0[4 + j] = (short)f2bf(a1[j]);
      af1[j]     = (short)f2bf(a2[j]);
      af1[4 + j] = (short)f2bf(a3[j]);
    }
    #pragma unroll
    for (int nt = 0; nt < 4; ++nt)
      acc[nt] = __builtin_amdgcn_mfma_f32_16x16x32_bf16(af0, bw[nt], acc[nt], 0, 0, 0);
    #pragma unroll
    for (int nt = 0; nt < 4; ++nt)
      acc[nt] = __builtin_amdgcn_mfma_f32_16x16x32_bf16(af1, bw[4 + nt], acc[nt], 0, 0, 0);
    if (more) {
      #pragma unroll
      for (int i = 0; i < 8; ++i) bw[i] = bn[i];
    }
  }

  __syncthreads();   // all waves done with xs; safe to reuse region as h2p

  // ---- partial h2 -> LDS (fp32). C/D: col(q)=lane&15 + nt*16, row=(lane>>4)*4+reg
  #pragma unroll
  for (int nt = 0; nt < 4; ++nt)
    #pragma unroll
    for (int j = 0; j < 4; ++j)
      h2p[kh][rt][hi4 * 4 + j][nt * 16 + lo16] = acc[nt][j];
  __syncthreads();

  // ---- combine both K-halves + bias, build A-frags for stage 2
  const int row = lo16;
  f4 u0 = *(const f4*)&h2p[0][rt][row][hi4 * 8];
  f4 u1 = *(const f4*)&h2p[0][rt][row][hi4 * 8 + 4];
  f4 v0 = *(const f4*)&h2p[1][rt][row][hi4 * 8];
  f4 v1 = *(const f4*)&h2p[1][rt][row][hi4 * 8 + 4];
  f4 u2 = *(const f4*)&h2p[0][rt][row][32 + hi4 * 8];
  f4 u3 = *(const f4*)&h2p[0][rt][row][32 + hi4 * 8 + 4];
  f4 v2 = *(const f4*)&h2p[1][rt][row][32 + hi4 * 8];
  f4 v3 = *(const f4*)&h2p[1][rt][row][32 + hi4 * 8 + 4];
  bf8 ha0, ha1;
  #pragma unroll
  for (int j = 0; j < 4; ++j) {
    ha0[j]     = (short)f2bf(u0[j] + v0[j] + bias_s[hi4 * 8 + j]);
    ha0[4 + j] = (short)f2bf(u1[j] + v1[j] + bias_s[hi4 * 8 + 4 + j]);
    ha1[j]     = (short)f2bf(u2[j] + v2[j] + bias_s[32 + hi4 * 8 + j]);
    ha1[4 + j] = (short)f2bf(u3[j] + v3[j] + bias_s[32 + hi4 * 8 + 4 + j]);
  }

  // ---- stage 2: 40 d-tiles for this wave, depth-1 W3F prefetch
  const float* upw = embed + b * EW + (EW - ND);
  float* outp = out + ((size_t)b * NS + wrow + hi4 * 4) * ND;
  const int dt0 = kh * 40;
  bf8 b0 = *(const bf8*)(W3F + (size_t)(dt0 * 64 + lane) * 8);
  bf8 b1 = *(const bf8*)(W3F + (size_t)((80 + dt0) * 64 + lane) * 8);

  for (int i = 0; i < 40; ++i) {
    const int dt  = dt0 + i;
    const int pdt = (i < 39) ? dt + 1 : dt;
    bf8 nb0 = *(const bf8*)(W3F + (size_t)(pdt * 64 + lane) * 8);
    bf8 nb1 = *(const bf8*)(W3F + (size_t)((80 + pdt) * 64 + lane) * 8);
    f4 o = {};
    o = __builtin_amdgcn_mfma_f32_16x16x32_bf16(ha0, b0, o, 0, 0, 0);
    o = __builtin_amdgcn_mfma_f32_16x16x32_bf16(ha1, b1, o, 0, 0, 0);
    const int d = dt * 16 + lo16;
    const float scale = upw[d];
    const float bu = b_up[d];
    #pragma unroll
    for (int j = 0; j < 4; ++j)
      outp[(size_t)j * ND + d] = (o[j] + bu) * scale;
    b0 = nb0; b1 = nb1;
  }
}

extern "C" void kernel_launch(void* const* d_in, const int* in_sizes, int n_in,
                              void* d_out, int out_size, void* d_ws, size_t ws_size,
                              hipStream_t stream) {
  const float* x      = (const float*)d_in[0];
  const float* embed  = (const float*)d_in[1];
  const float* w_down = (const float*)d_in[2];
  const float* b_down = (const float*)d_in[3];
  const float* w_up   = (const float*)d_in[4];
  const float* b_up   = (const float*)d_in[5];
  float* out = (float*)d_out;

  unsigned short* W2F = (unsigned short*)d_ws;            // 655360 shorts (1.31 MB)
  unsigned short* W3F = W2F + 8 * 40 * 4 * 512;           // 81920 shorts (164 KB)
  float* h2bias = (float*)(W3F + 2 * 80 * 64 * 8);        // 512 floats

  prep_all<<<481, 256, 0, stream>>>(embed, w_down, w_up, b_down, W2F, W3F, h2bias);
  fused_main<<<1024, 256, 0, stream>>>(x, embed, b_up, W2F, W3F, h2bias, out);
}

// Round 5
// 104.923 us; speedup vs baseline: 1.2388x; 1.1819x over previous
//
#include <hip/hip_runtime.h>
#include <hip/hip_bf16.h>

#define NB 8
#define NS 4096
#define ND 1280
#define NR 64
#define EW 6656   // D + R*R + D

typedef __attribute__((ext_vector_type(4))) float f4;
typedef __attribute__((ext_vector_type(8))) short bf8;

union BF8U { bf8 v; unsigned u[4]; };

__device__ __forceinline__ unsigned short f2bf(float f) {
  union { float f; unsigned u; } v; v.f = f;
  unsigned u = v.u + 0x7FFFu + ((v.u >> 16) & 1u);  // RNE
  return (unsigned short)(u >> 16);
}

__device__ __forceinline__ unsigned pk2(float a, float b) {
  __hip_bfloat162 t = __float22bfloat162_rn(float2{a, b});   // v_cvt_pk_bf16_f32 (RNE)
  return *reinterpret_cast<unsigned*>(&t);
}

// ---------------- prep (merged): W2F, W3F, h2bias ----------------
// W2F frag layout: index = ((b*40 + kt)*4 + nt)*512 + lane*8 + j
//   kt = d/32, nt = q/16, lane = ((d%32)/8)*16 + (q%16), j = d%8
// W3F index = ((kt*80 + nt)*64 + lane)*8 + j ; kt=q/32, nt=d/16,
//   lane=((q%32)/8)*16 + d%16, j=q%8   (serves BOTH B-operand in old path
//   and A-operand in swapped path: same bytes)
__global__ __launch_bounds__(256) void prep_all(const float* __restrict__ embed,
                                                const float* __restrict__ w_down,
                                                const float* __restrict__ w_up,
                                                const float* __restrict__ b_down,
                                                unsigned short* __restrict__ W2F,
                                                unsigned short* __restrict__ W3F,
                                                float* __restrict__ h2bias) {
  const int blk = blockIdx.x;
  const int t   = threadIdx.x;
  if (blk < 160) {
    const int b  = blk / 20;
    const int qg = (blk % 20) / 5;
    const int dg = blk % 5;
    __shared__ float mids[16][64];
    #pragma unroll
    for (int i = 0; i < 4; ++i) {
      int idx = t + i * 256;
      mids[idx >> 6][idx & 63] = embed[b * EW + ND + qg * 1024 + idx];
    }
    __syncthreads();
    const int d = dg * 256 + t;
    float acc[16];
    #pragma unroll
    for (int q = 0; q < 16; ++q) acc[q] = 0.f;
    for (int r = 0; r < 64; r += 8) {
      float wd[8];
      #pragma unroll
      for (int u = 0; u < 8; ++u) wd[u] = w_down[(r + u) * ND + d];
      #pragma unroll
      for (int u = 0; u < 8; ++u)
        #pragma unroll
        for (int q = 0; q < 16; ++q) acc[q] += mids[q][r + u] * wd[u];
    }
    const float dwn = embed[b * EW + d];
    const int kt = d >> 5, lanehi = (d & 31) >> 3, jj = d & 7;
    #pragma unroll
    for (int q = 0; q < 16; ++q)
      W2F[(((b * 40 + kt) * 4 + qg) << 9) + (lanehi * 16 + q) * 8 + jj] = f2bf(acc[q] * dwn);
  } else if (blk < 480) {
    int g = (blk - 160) * 256 + t;            // g = d*64 + q
    int d = g >> 6, q = g & 63;
    int kt = q >> 5, nt = d >> 4, lanei = ((q & 31) >> 3) * 16 + (d & 15), jj = q & 7;
    W3F[((kt * 80 + nt) * 64 + lanei) * 8 + jj] = f2bf(w_up[g]);
  } else {
    #pragma unroll
    for (int ii = 0; ii < 2; ++ii) {
      int id = ii * 256 + t;                  // id = b*64 + q
      int bb = id >> 6, q = id & 63;
      float s = 0.f;
      for (int r = 0; r < 64; ++r) s += b_down[r] * embed[bb * EW + ND + q * 64 + r];
      h2bias[id] = s;
    }
  }
}

// ---------------- K1: read-streamer -> h2F (bf16 frag-ordered, 4 MB) ----------------
// Block: 32 rows of one batch; 4 waves = 2 row-tiles (rt) x 2 K-halves (kh).
// h2F layout (uint4 units): [((b*256 + tile*2 + rt)*2 + kt)*64 + lane]
//   = B/A-frag for 16 rows x q in [kt*32, kt*32+32)
__global__ __launch_bounds__(256) void k1_h2(const float* __restrict__ x,
                                             const unsigned short* __restrict__ W2F,
                                             const float* __restrict__ h2bias,
                                             uint4* __restrict__ h2F) {
  const int tid  = threadIdx.x;
  const int lane = tid & 63;
  const int w    = tid >> 6;
  const int kh   = w >> 1;
  const int rt   = w & 1;
  const int b    = blockIdx.x & 7;
  const int tile = blockIdx.x >> 3;       // 0..127
  const int lo16 = lane & 15;
  const int hi4  = lane >> 4;
  const int wrow = tile * 32 + rt * 16;

  __shared__ __align__(16) char smem[32768];
  float (*xs)[2][1024]    = (float (*)[2][1024])smem;     // [wave][buf][16x64]
  float (*h2p)[2][16][68] = (float (*)[2][16][68])smem;   // aliases xs (barrier-separated)

  const float* xbase = x + ((size_t)b * NS + wrow) * ND + kh * 640;
  const unsigned short* w2b = W2F + (size_t)b * 81920;

  #define ISSUE_DMA(ck, buf)                                                         \
    _Pragma("unroll")                                                                \
    for (int it = 0; it < 4; ++it) {                                                 \
      const int rloc = it * 4 + hi4;                                                 \
      const int cf   = lo16 ^ rloc;                                                  \
      const float* src = xbase + (size_t)rloc * ND + (ck) * 64 + cf * 4;             \
      __builtin_amdgcn_global_load_lds((__attribute__((address_space(1))) void*)src, \
          (__attribute__((address_space(3))) void*)&xs[w][buf][it * 256], 16, 0, 0); \
    }

  f4 acc[4] = {};
  bf8 bw[8];

  ISSUE_DMA(0, 0)
  {
    const unsigned short* wp = w2b + (((kh * 10) * 8) << 9) + lane * 8;
    #pragma unroll
    for (int i = 0; i < 8; ++i) bw[i] = *(const bf8*)(wp + (i << 9));
  }

  for (int ck = 0; ck < 10; ++ck) {
    const int buf = ck & 1;
    asm volatile("s_waitcnt vmcnt(0)" ::: "memory");
    const f4* xp = (const f4*)&xs[w][buf][0];
    f4 a0 = xp[lo16 * 16 + ((hi4 * 2)     ^ lo16)];
    f4 a1 = xp[lo16 * 16 + ((hi4 * 2 + 1) ^ lo16)];
    f4 a2 = xp[lo16 * 16 + ((hi4 * 2 + 8) ^ lo16)];
    f4 a3 = xp[lo16 * 16 + ((hi4 * 2 + 9) ^ lo16)];
    bf8 bn[8];
    const bool more = (ck < 9);
    if (more) {
      ISSUE_DMA(ck + 1, buf ^ 1)
      const unsigned short* wp = w2b + (size_t)(((kh * 10 + ck + 1) * 8) << 9) + lane * 8;
      #pragma unroll
      for (int i = 0; i < 8; ++i) bn[i] = *(const bf8*)(wp + (i << 9));
    }
    BF8U af0, af1;
    af0.u[0] = pk2(a0[0], a0[1]); af0.u[1] = pk2(a0[2], a0[3]);
    af0.u[2] = pk2(a1[0], a1[1]); af0.u[3] = pk2(a1[2], a1[3]);
    af1.u[0] = pk2(a2[0], a2[1]); af1.u[1] = pk2(a2[2], a2[3]);
    af1.u[2] = pk2(a3[0], a3[1]); af1.u[3] = pk2(a3[2], a3[3]);
    #pragma unroll
    for (int nt = 0; nt < 4; ++nt)
      acc[nt] = __builtin_amdgcn_mfma_f32_16x16x32_bf16(af0.v, bw[nt], acc[nt], 0, 0, 0);
    #pragma unroll
    for (int nt = 0; nt < 4; ++nt)
      acc[nt] = __builtin_amdgcn_mfma_f32_16x16x32_bf16(af1.v, bw[4 + nt], acc[nt], 0, 0, 0);
    if (more) {
      #pragma unroll
      for (int i = 0; i < 8; ++i) bw[i] = bn[i];
    }
  }

  __syncthreads();   // all waves done reading xs; reuse region as h2p

  // partial h2 -> LDS (fp32). C/D: col(q)=nt*16+lo16, row=hi4*4+reg
  #pragma unroll
  for (int nt = 0; nt < 4; ++nt)
    #pragma unroll
    for (int j = 0; j < 4; ++j)
      h2p[kh][rt][hi4 * 4 + j][nt * 16 + lo16] = acc[nt][j];
  __syncthreads();

  // combine: wave (kh,rt) builds frag for q in [kh*32, kh*32+32), rows of rt.
  // lane: row s = lo16, q = kh*32 + hi4*8 + (0..7)
  const int q0 = kh * 32 + hi4 * 8;
  f4 u0 = *(const f4*)&h2p[0][rt][lo16][q0];
  f4 u1 = *(const f4*)&h2p[0][rt][lo16][q0 + 4];
  f4 v0 = *(const f4*)&h2p[1][rt][lo16][q0];
  f4 v1 = *(const f4*)&h2p[1][rt][lo16][q0 + 4];
  f4 c0 = *(const f4*)(h2bias + b * 64 + q0);
  f4 c1 = *(const f4*)(h2bias + b * 64 + q0 + 4);
  float s[8];
  #pragma unroll
  for (int j = 0; j < 4; ++j) {
    s[j]     = u0[j] + v0[j] + c0[j];
    s[4 + j] = u1[j] + v1[j] + c1[j];
  }
  uint4 pk;
  pk.x = pk2(s[0], s[1]); pk.y = pk2(s[2], s[3]);
  pk.z = pk2(s[4], s[5]); pk.w = pk2(s[6], s[7]);
  h2F[(size_t)(((b * 256 + tile * 2 + rt) * 2 + kh) * 64 + lane)] = pk;
}

// ---------------- K2: write-streamer ----------------
// Block: 32 rows; 4 waves = 2 row-tiles (rt) x 2 d-halves (kh, 640 cols each).
// Swapped MFMA: o = mfma(W3frag, h2frag) -> C row = d-within-tile (=hi4*4+j),
// col = s (=lo16). Lane's f4 = 4 consecutive d of one row s.
// Epilogue through wave-private LDS -> stores are 1KB, 256B/row segments.
__global__ __launch_bounds__(256) void k2_out(const uint4* __restrict__ h2F,
                                              const float* __restrict__ embed,
                                              const float* __restrict__ b_up,
                                              const unsigned short* __restrict__ W3F,
                                              float* __restrict__ out) {
  const int tid  = threadIdx.x;
  const int lane = tid & 63;
  const int w    = tid >> 6;
  const int kh   = w >> 1;                // d-half
  const int rt   = w & 1;                 // row-tile
  const int b    = blockIdx.x & 7;
  const int t2   = blockIdx.x >> 3;       // 0..127
  const int lo16 = lane & 15;
  const int hi4  = lane >> 4;

  __shared__ __align__(16) float lds[4][16][68];   // per-wave transpose buffer

  const int tile16 = t2 * 2 + rt;
  uint4 hv0 = h2F[(size_t)(((b * 256 + tile16) * 2 + 0) * 64 + lane)];
  uint4 hv1 = h2F[(size_t)(((b * 256 + tile16) * 2 + 1) * 64 + lane)];
  BF8U ha0, ha1;
  ha0.u[0] = hv0.x; ha0.u[1] = hv0.y; ha0.u[2] = hv0.z; ha0.u[3] = hv0.w;
  ha1.u[0] = hv1.x; ha1.u[1] = hv1.y; ha1.u[2] = hv1.z; ha1.u[3] = hv1.w;

  const int d0 = kh * 640;
  const float* upw = embed + b * EW + (EW - ND) + d0;
  const float* bup = b_up + d0;
  float* outp = out + ((size_t)b * NS + t2 * 32 + rt * 16) * ND + d0;
  const int dtbase = kh * 40;

  // depth-1 prefetch of W3F chunks (4 d-tiles x 2 kt each)
  bf8 wb[4][2];
  #pragma unroll
  for (int i = 0; i < 4; ++i) {
    const int dt = dtbase + i;
    wb[i][0] = *(const bf8*)(W3F + (size_t)(dt * 64 + lane) * 8);
    wb[i][1] = *(const bf8*)(W3F + (size_t)((80 + dt) * 64 + lane) * 8);
  }

  for (int c = 0; c < 10; ++c) {
    f4 o[4];
    #pragma unroll
    for (int i = 0; i < 4; ++i) {
      f4 t = {};
      t = __builtin_amdgcn_mfma_f32_16x16x32_bf16(wb[i][0], ha0.v, t, 0, 0, 0);
      t = __builtin_amdgcn_mfma_f32_16x16x32_bf16(wb[i][1], ha1.v, t, 0, 0, 0);
      o[i] = t;
    }
    bf8 wn[4][2];
    if (c < 9) {
      #pragma unroll
      for (int i = 0; i < 4; ++i) {
        const int dt = dtbase + (c + 1) * 4 + i;
        wn[i][0] = *(const bf8*)(W3F + (size_t)(dt * 64 + lane) * 8);
        wn[i][1] = *(const bf8*)(W3F + (size_t)((80 + dt) * 64 + lane) * 8);
      }
    }
    // epilogue: (o + b_up) * up_w, to LDS (row s = lo16, col = i*16 + hi4*4)
    #pragma unroll
    for (int i = 0; i < 4; ++i) {
      const int dl = c * 64 + i * 16 + hi4 * 4;
      f4 sc = *(const f4*)(upw + dl);
      f4 bu = *(const f4*)(bup + dl);
      f4 r;
      #pragma unroll
      for (int j = 0; j < 4; ++j) r[j] = (o[i][j] + bu[j]) * sc[j];
      *(f4*)&lds[w][lo16][i * 16 + hi4 * 4] = r;
    }
    // transposed read + 1KB stores: instr k: rows 4k+hi4, cols lo16*4 (256B/row)
    #pragma unroll
    for (int k = 0; k < 4; ++k) {
      f4 v = *(const f4*)&lds[w][4 * k + hi4][lo16 * 4];
      *(f4*)(outp + (size_t)(4 * k + hi4) * ND + c * 64 + lo16 * 4) = v;
    }
    #pragma unroll
    for (int i = 0; i < 4; ++i) { wb[i][0] = wn[i][0]; wb[i][1] = wn[i][1]; }
  }
}

// ---------------- R4 fused fallback (used only if ws too small) ----------------
__global__ __launch_bounds__(256, 4) void fused_main(const float* __restrict__ x,
                                                     const float* __restrict__ embed,
                                                     const float* __restrict__ b_up,
                                                     const unsigned short* __restrict__ W2F,
                                                     const unsigned short* __restrict__ W3F,
                                                     const float* __restrict__ h2bias,
                                                     float* __restrict__ out) {
  const int tid  = threadIdx.x;
  const int lane = tid & 63;
  const int w    = tid >> 6;
  const int kh   = w >> 1;
  const int rt   = w & 1;
  const int b    = blockIdx.x & 7;
  const int tile = blockIdx.x >> 3;
  const int lo16 = lane & 15;
  const int hi4  = lane >> 4;
  const int wrow = tile * 32 + rt * 16;

  __shared__ __align__(16) char smem[32768 + 256];
  float (*xs)[2][1024]    = (float (*)[2][1024])smem;
  float (*h2p)[2][16][68] = (float (*)[2][16][68])smem;
  float* bias_s           = (float*)(smem + 32768);

  if (tid < 64) bias_s[tid] = h2bias[b * 64 + tid];

  const float* xbase = x + ((size_t)b * NS + wrow) * ND + kh * 640;
  const unsigned short* w2b = W2F + (size_t)b * 81920;

  f4 acc[4] = {};
  bf8 bw[8];
  ISSUE_DMA(0, 0)
  {
    const unsigned short* wp = w2b + (((kh * 10) * 8) << 9) + lane * 8;
    #pragma unroll
    for (int i = 0; i < 8; ++i) bw[i] = *(const bf8*)(wp + (i << 9));
  }
  for (int ck = 0; ck < 10; ++ck) {
    const int buf = ck & 1;
    asm volatile("s_waitcnt vmcnt(0)" ::: "memory");
    const f4* xp = (const f4*)&xs[w][buf][0];
    f4 a0 = xp[lo16 * 16 + ((hi4 * 2)     ^ lo16)];
    f4 a1 = xp[lo16 * 16 + ((hi4 * 2 + 1) ^ lo16)];
    f4 a2 = xp[lo16 * 16 + ((hi4 * 2 + 8) ^ lo16)];
    f4 a3 = xp[lo16 * 16 + ((hi4 * 2 + 9) ^ lo16)];
    bf8 bn[8];
    const bool more = (ck < 9);
    if (more) {
      ISSUE_DMA(ck + 1, buf ^ 1)
      const unsigned short* wp = w2b + (size_t)(((kh * 10 + ck + 1) * 8) << 9) + lane * 8;
      #pragma unroll
      for (int i = 0; i < 8; ++i) bn[i] = *(const bf8*)(wp + (i << 9));
    }
    BF8U af0, af1;
    af0.u[0] = pk2(a0[0], a0[1]); af0.u[1] = pk2(a0[2], a0[3]);
    af0.u[2] = pk2(a1[0], a1[1]); af0.u[3] = pk2(a1[2], a1[3]);
    af1.u[0] = pk2(a2[0], a2[1]); af1.u[1] = pk2(a2[2], a2[3]);
    af1.u[2] = pk2(a3[0], a3[1]); af1.u[3] = pk2(a3[2], a3[3]);
    #pragma unroll
    for (int nt = 0; nt < 4; ++nt)
      acc[nt] = __builtin_amdgcn_mfma_f32_16x16x32_bf16(af0.v, bw[nt], acc[nt], 0, 0, 0);
    #pragma unroll
    for (int nt = 0; nt < 4; ++nt)
      acc[nt] = __builtin_amdgcn_mfma_f32_16x16x32_bf16(af1.v, bw[4 + nt], acc[nt], 0, 0, 0);
    if (more) {
      #pragma unroll
      for (int i = 0; i < 8; ++i) bw[i] = bn[i];
    }
  }
  __syncthreads();
  #pragma unroll
  for (int nt = 0; nt < 4; ++nt)
    #pragma unroll
    for (int j = 0; j < 4; ++j)
      h2p[kh][rt][hi4 * 4 + j][nt * 16 + lo16] = acc[nt][j];
  __syncthreads();
  const int row = lo16;
  f4 u0 = *(const f4*)&h2p[0][rt][row][hi4 * 8];
  f4 u1 = *(const f4*)&h2p[0][rt][row][hi4 * 8 + 4];
  f4 v0 = *(const f4*)&h2p[1][rt][row][hi4 * 8];
  f4 v1 = *(const f4*)&h2p[1][rt][row][hi4 * 8 + 4];
  f4 u2 = *(const f4*)&h2p[0][rt][row][32 + hi4 * 8];
  f4 u3 = *(const f4*)&h2p[0][rt][row][32 + hi4 * 8 + 4];
  f4 v2 = *(const f4*)&h2p[1][rt][row][32 + hi4 * 8];
  f4 v3 = *(const f4*)&h2p[1][rt][row][32 + hi4 * 8 + 4];
  bf8 ha0, ha1;
  #pragma unroll
  for (int j = 0; j < 4; ++j) {
    ha0[j]     = (short)f2bf(u0[j] + v0[j] + bias_s[hi4 * 8 + j]);
    ha0[4 + j] = (short)f2bf(u1[j] + v1[j] + bias_s[hi4 * 8 + 4 + j]);
    ha1[j]     = (short)f2bf(u2[j] + v2[j] + bias_s[32 + hi4 * 8 + j]);
    ha1[4 + j] = (short)f2bf(u3[j] + v3[j] + bias_s[32 + hi4 * 8 + 4 + j]);
  }
  const float* upw = embed + b * EW + (EW - ND);
  float* outp = out + ((size_t)b * NS + wrow + hi4 * 4) * ND;
  const int dt0 = kh * 40;
  bf8 b0 = *(const bf8*)(W3F + (size_t)(dt0 * 64 + lane) * 8);
  bf8 b1 = *(const bf8*)(W3F + (size_t)((80 + dt0) * 64 + lane) * 8);
  for (int i = 0; i < 40; ++i) {
    const int dt  = dt0 + i;
    const int pdt = (i < 39) ? dt + 1 : dt;
    bf8 nb0 = *(const bf8*)(W3F + (size_t)(pdt * 64 + lane) * 8);
    bf8 nb1 = *(const bf8*)(W3F + (size_t)((80 + pdt) * 64 + lane) * 8);
    f4 o = {};
    o = __builtin_amdgcn_mfma_f32_16x16x32_bf16(ha0, b0, o, 0, 0, 0);
    o = __builtin_amdgcn_mfma_f32_16x16x32_bf16(ha1, b1, o, 0, 0, 0);
    const int d = dt * 16 + lo16;
    const float scale = upw[d];
    const float bu = b_up[d];
    #pragma unroll
    for (int j = 0; j < 4; ++j)
      outp[(size_t)j * ND + d] = (o[j] + bu) * scale;
    b0 = nb0; b1 = nb1;
  }
}

extern "C" void kernel_launch(void* const* d_in, const int* in_sizes, int n_in,
                              void* d_out, int out_size, void* d_ws, size_t ws_size,
                              hipStream_t stream) {
  const float* x      = (const float*)d_in[0];
  const float* embed  = (const float*)d_in[1];
  const float* w_down = (const float*)d_in[2];
  const float* b_down = (const float*)d_in[3];
  const float* w_up   = (const float*)d_in[4];
  const float* b_up   = (const float*)d_in[5];
  float* out = (float*)d_out;

  char* ws = (char*)d_ws;
  unsigned short* W2F = (unsigned short*)ws;                 // 1,310,720 B
  unsigned short* W3F = (unsigned short*)(ws + 1310720);     //   163,840 B
  float* h2bias       = (float*)(ws + 1474560);              //     2,048 B
  uint4* h2F          = (uint4*)(ws + 1476608);              // 4,194,304 B
  const size_t need   = 1476608 + 4194304;

  prep_all<<<481, 256, 0, stream>>>(embed, w_down, w_up, b_down, W2F, W3F, h2bias);
  if (ws_size >= need) {
    k1_h2 <<<1024, 256, 0, stream>>>(x, W2F, h2bias, h2F);
    k2_out<<<1024, 256, 0, stream>>>(h2F, embed, b_up, W3F, out);
  } else {
    fused_main<<<1024, 256, 0, stream>>>(x, embed, b_up, W2F, W3F, h2bias, out);
  }
}

// Round 6
// 102.854 us; speedup vs baseline: 1.2637x; 1.0201x over previous
//
#include <hip/hip_runtime.h>
#include <hip/hip_bf16.h>

#define NB 8
#define NS 4096
#define ND 1280
#define NR 64
#define EW 6656   // D + R*R + D

typedef __attribute__((ext_vector_type(4))) float f4;
typedef __attribute__((ext_vector_type(8))) short bf8;

union BF8U { bf8 v; unsigned u[4]; };

__device__ __forceinline__ unsigned short f2bf(float f) {
  union { float f; unsigned u; } v; v.f = f;
  unsigned u = v.u + 0x7FFFu + ((v.u >> 16) & 1u);  // RNE
  return (unsigned short)(u >> 16);
}

__device__ __forceinline__ unsigned pk2(float a, float b) {
  __hip_bfloat162 t = __float22bfloat162_rn(float2{a, b});   // v_cvt_pk_bf16_f32
  return *reinterpret_cast<unsigned*>(&t);
}

// ---------------- prep: W2F, W3FB (per-batch, up_w folded), h2bias ----------------
// W2F frag: idx = ((b*40 + kt)*4 + nt)*512 + lane*8 + j
//   kt = d/32, nt = q/16, lane = ((d%32)/8)*16 + (q%16), j = d%8
// W3FB[b] frag (A-operand of swapped MFMA, value = w_up[d,q]*up_w[b,d]):
//   idx = b*81920 + ((kt*80 + nt)*64 + lane)*8 + j ; kt=q/32, nt=d/16,
//   lane = ((q%32)/8)*16 + d%16, j = q%8
__global__ __launch_bounds__(256) void prep_all(const float* __restrict__ embed,
                                                const float* __restrict__ w_down,
                                                const float* __restrict__ w_up,
                                                const float* __restrict__ b_down,
                                                unsigned short* __restrict__ W2F,
                                                unsigned short* __restrict__ W3FB,
                                                float* __restrict__ h2bias) {
  const int blk = blockIdx.x;
  const int t   = threadIdx.x;
  if (blk < 160) {
    const int b  = blk / 20;
    const int qg = (blk % 20) / 5;
    const int dg = blk % 5;
    __shared__ float mids[16][64];
    #pragma unroll
    for (int i = 0; i < 4; ++i) {
      int idx = t + i * 256;
      mids[idx >> 6][idx & 63] = embed[b * EW + ND + qg * 1024 + idx];
    }
    __syncthreads();
    const int d = dg * 256 + t;
    float acc[16];
    #pragma unroll
    for (int q = 0; q < 16; ++q) acc[q] = 0.f;
    for (int r = 0; r < 64; r += 8) {
      float wd[8];
      #pragma unroll
      for (int u = 0; u < 8; ++u) wd[u] = w_down[(r + u) * ND + d];
      #pragma unroll
      for (int u = 0; u < 8; ++u)
        #pragma unroll
        for (int q = 0; q < 16; ++q) acc[q] += mids[q][r + u] * wd[u];
    }
    const float dwn = embed[b * EW + d];
    const int kt = d >> 5, lanehi = (d & 31) >> 3, jj = d & 7;
    #pragma unroll
    for (int q = 0; q < 16; ++q)
      W2F[(((b * 40 + kt) * 4 + qg) << 9) + (lanehi * 16 + q) * 8 + jj] = f2bf(acc[q] * dwn);
  } else if (blk < 2720) {
    const int local = blk - 160;
    const int b  = local / 320;
    const int g  = (local % 320) * 256 + t;   // g = d*64 + q
    const int d  = g >> 6, q = g & 63;
    const int kt = q >> 5, nt = d >> 4;
    const int lanei = ((q & 31) >> 3) * 16 + (d & 15), jj = q & 7;
    const float upw = embed[b * EW + 5376 + d];
    W3FB[(size_t)b * 81920 + ((kt * 80 + nt) * 64 + lanei) * 8 + jj] = f2bf(w_up[g] * upw);
  } else {
    #pragma unroll
    for (int ii = 0; ii < 2; ++ii) {
      int id = ii * 256 + t;                  // id = b*64 + q
      int bb = id >> 6, q = id & 63;
      float s = 0.f;
      for (int r = 0; r < 64; ++r) s += b_down[r] * embed[bb * EW + ND + q * 64 + r];
      h2bias[id] = s;
    }
  }
}

// ---------------- K1: read-streamer -> h2F (bf16 frag-ordered, 4 MB) ----------------
// Block: 32 rows of one batch; 4 waves = 2 row-tiles (rt) x 2 K-halves (kh).
// Counted-vmcnt pipeline: issue chunk ck+1 (4 DMA + 8 W2F loads), then
// s_waitcnt vmcnt(12) -> waits only the 12 loads of chunk ck (T4: never drain to 0).
__global__ __launch_bounds__(256, 4) void k1_h2(const float* __restrict__ x,
                                                const unsigned short* __restrict__ W2F,
                                                const float* __restrict__ h2bias,
                                                uint4* __restrict__ h2F) {
  const int tid  = threadIdx.x;
  const int lane = tid & 63;
  const int w    = tid >> 6;
  const int kh   = w >> 1;
  const int rt   = w & 1;
  const int b    = blockIdx.x & 7;
  const int tile = blockIdx.x >> 3;       // 0..127
  const int lo16 = lane & 15;
  const int hi4  = lane >> 4;
  const int wrow = tile * 32 + rt * 16;

  __shared__ __align__(16) char smem[32768];
  float (*xs)[2][1024]    = (float (*)[2][1024])smem;     // [wave][buf][16x64]
  float (*h2p)[2][16][68] = (float (*)[2][16][68])smem;   // aliases xs (barrier-separated)

  const float* xbase = x + ((size_t)b * NS + wrow) * ND + kh * 640;
  const unsigned short* w2b = W2F + (size_t)b * 81920;

  #define ISSUE_DMA(ck, buf)                                                         \
    _Pragma("unroll")                                                                \
    for (int it = 0; it < 4; ++it) {                                                 \
      const int rloc = it * 4 + hi4;                                                 \
      const int cf   = lo16 ^ rloc;                                                  \
      const float* src = xbase + (size_t)rloc * ND + (ck) * 64 + cf * 4;             \
      __builtin_amdgcn_global_load_lds((__attribute__((address_space(1))) void*)src, \
          (__attribute__((address_space(3))) void*)&xs[w][buf][it * 256], 16, 0, 0); \
    }

  f4 acc[4] = {};
  bf8 bw[8];

  ISSUE_DMA(0, 0)
  {
    const unsigned short* wp = w2b + (((kh * 10) * 8) << 9) + lane * 8;
    #pragma unroll
    for (int i = 0; i < 8; ++i) bw[i] = *(const bf8*)(wp + (i << 9));
  }

  for (int ck = 0; ck < 10; ++ck) {
    const int buf = ck & 1;
    bf8 bn[8];
    if (ck < 9) {
      // issue next chunk FIRST (12 younger loads), then wait only the old 12
      ISSUE_DMA(ck + 1, buf ^ 1)
      const unsigned short* wp = w2b + (size_t)(((kh * 10 + ck + 1) * 8) << 9) + lane * 8;
      #pragma unroll
      for (int i = 0; i < 8; ++i) bn[i] = *(const bf8*)(wp + (i << 9));
      asm volatile("s_waitcnt vmcnt(12)" ::: "memory");
    } else {
      asm volatile("s_waitcnt vmcnt(0)" ::: "memory");
    }
    const f4* xp = (const f4*)&xs[w][buf][0];
    f4 a0 = xp[lo16 * 16 + ((hi4 * 2)     ^ lo16)];
    f4 a1 = xp[lo16 * 16 + ((hi4 * 2 + 1) ^ lo16)];
    f4 a2 = xp[lo16 * 16 + ((hi4 * 2 + 8) ^ lo16)];
    f4 a3 = xp[lo16 * 16 + ((hi4 * 2 + 9) ^ lo16)];
    BF8U af0, af1;
    af0.u[0] = pk2(a0[0], a0[1]); af0.u[1] = pk2(a0[2], a0[3]);
    af0.u[2] = pk2(a1[0], a1[1]); af0.u[3] = pk2(a1[2], a1[3]);
    af1.u[0] = pk2(a2[0], a2[1]); af1.u[1] = pk2(a2[2], a2[3]);
    af1.u[2] = pk2(a3[0], a3[1]); af1.u[3] = pk2(a3[2], a3[3]);
    #pragma unroll
    for (int nt = 0; nt < 4; ++nt)
      acc[nt] = __builtin_amdgcn_mfma_f32_16x16x32_bf16(af0.v, bw[nt], acc[nt], 0, 0, 0);
    #pragma unroll
    for (int nt = 0; nt < 4; ++nt)
      acc[nt] = __builtin_amdgcn_mfma_f32_16x16x32_bf16(af1.v, bw[4 + nt], acc[nt], 0, 0, 0);
    if (ck < 9) {
      #pragma unroll
      for (int i = 0; i < 8; ++i) bw[i] = bn[i];
    }
  }

  __syncthreads();   // all waves done reading xs; reuse region as h2p

  // partial h2 -> LDS (fp32). C/D: col(q)=nt*16+lo16, row=hi4*4+reg
  #pragma unroll
  for (int nt = 0; nt < 4; ++nt)
    #pragma unroll
    for (int j = 0; j < 4; ++j)
      h2p[kh][rt][hi4 * 4 + j][nt * 16 + lo16] = acc[nt][j];
  __syncthreads();

  // combine: wave (kh,rt) builds frag for q in [kh*32,kh*32+32), rows of rt.
  const int q0 = kh * 32 + hi4 * 8;
  f4 u0 = *(const f4*)&h2p[0][rt][lo16][q0];
  f4 u1 = *(const f4*)&h2p[0][rt][lo16][q0 + 4];
  f4 v0 = *(const f4*)&h2p[1][rt][lo16][q0];
  f4 v1 = *(const f4*)&h2p[1][rt][lo16][q0 + 4];
  f4 c0 = *(const f4*)(h2bias + b * 64 + q0);
  f4 c1 = *(const f4*)(h2bias + b * 64 + q0 + 4);
  float s[8];
  #pragma unroll
  for (int j = 0; j < 4; ++j) {
    s[j]     = u0[j] + v0[j] + c0[j];
    s[4 + j] = u1[j] + v1[j] + c1[j];
  }
  uint4 pk;
  pk.x = pk2(s[0], s[1]); pk.y = pk2(s[2], s[3]);
  pk.z = pk2(s[4], s[5]); pk.w = pk2(s[6], s[7]);
  h2F[(size_t)(((b * 256 + tile * 2 + rt) * 2 + kh) * 64 + lane)] = pk;
}

// ---------------- K2: write-streamer ----------------
// Block: 32 rows; 4 waves = 2 row-tiles (rt) x 2 d-halves (kh, 640 cols each).
// Swapped MFMA: o = mfma(W3FBfrag, h2frag): row = d-within-tile (hi4*4+j), col = s (lo16).
// up_w folded into W3FB; b_up*up_w staged in LDS once -> NO in-loop global loads
// except depth-1 W3FB prefetch, always issued BEFORE stores (no wait-on-store).
__global__ __launch_bounds__(256, 4) void k2_out(const uint4* __restrict__ h2F,
                                                 const float* __restrict__ embed,
                                                 const float* __restrict__ b_up,
                                                 const unsigned short* __restrict__ W3FB,
                                                 float* __restrict__ out) {
  const int tid  = threadIdx.x;
  const int lane = tid & 63;
  const int w    = tid >> 6;
  const int kh   = w >> 1;                // d-half
  const int rt   = w & 1;                 // row-tile
  const int b    = blockIdx.x & 7;
  const int t2   = blockIdx.x >> 3;       // 0..127
  const int lo16 = lane & 15;
  const int hi4  = lane >> 4;

  __shared__ __align__(16) float lds[4][16][36];   // per-wave transpose buffer (9.2 KB)
  __shared__ __align__(16) float pbs[1280];        // b_up * up_w for this batch

  // h2 frags for this wave's 16 rows
  const int tile16 = t2 * 2 + rt;
  uint4 hv0 = h2F[(size_t)(((b * 256 + tile16) * 2 + 0) * 64 + lane)];
  uint4 hv1 = h2F[(size_t)(((b * 256 + tile16) * 2 + 1) * 64 + lane)];

  // stage pb = b_up * up_w into LDS (once per block)
  const float* upw = embed + b * EW + 5376;
  #pragma unroll
  for (int i = 0; i < 5; ++i) {
    const int idx = i * 256 + tid;
    pbs[idx] = b_up[idx] * upw[idx];
  }
  __syncthreads();

  BF8U ha0, ha1;
  ha0.u[0] = hv0.x; ha0.u[1] = hv0.y; ha0.u[2] = hv0.z; ha0.u[3] = hv0.w;
  ha1.u[0] = hv1.x; ha1.u[1] = hv1.y; ha1.u[2] = hv1.z; ha1.u[3] = hv1.w;

  const unsigned short* w3b = W3FB + (size_t)b * 81920;
  float* outp = out + ((size_t)b * NS + t2 * 32 + rt * 16) * ND + kh * 640;
  const int dtbase = kh * 40;

  // depth-1 prefetch: 2 d-tiles x 2 kt
  bf8 wb00 = *(const bf8*)(w3b + (size_t)((dtbase)      * 64 + lane) * 8);
  bf8 wb01 = *(const bf8*)(w3b + (size_t)((80 + dtbase) * 64 + lane) * 8);
  bf8 wb10 = *(const bf8*)(w3b + (size_t)((dtbase + 1)      * 64 + lane) * 8);
  bf8 wb11 = *(const bf8*)(w3b + (size_t)((80 + dtbase + 1) * 64 + lane) * 8);

  for (int c = 0; c < 20; ++c) {
    f4 o0 = {}, o1 = {};
    o0 = __builtin_amdgcn_mfma_f32_16x16x32_bf16(wb00, ha0.v, o0, 0, 0, 0);
    o0 = __builtin_amdgcn_mfma_f32_16x16x32_bf16(wb01, ha1.v, o0, 0, 0, 0);
    o1 = __builtin_amdgcn_mfma_f32_16x16x32_bf16(wb10, ha0.v, o1, 0, 0, 0);
    o1 = __builtin_amdgcn_mfma_f32_16x16x32_bf16(wb11, ha1.v, o1, 0, 0, 0);
    // prefetch next step BEFORE the stores (loads stay older than stores)
    if (c < 19) {
      const int dt = dtbase + (c + 1) * 2;
      wb00 = *(const bf8*)(w3b + (size_t)(dt * 64 + lane) * 8);
      wb01 = *(const bf8*)(w3b + (size_t)((80 + dt) * 64 + lane) * 8);
      wb10 = *(const bf8*)(w3b + (size_t)((dt + 1) * 64 + lane) * 8);
      wb11 = *(const bf8*)(w3b + (size_t)((80 + dt + 1) * 64 + lane) * 8);
    }
    // epilogue: o + pb -> LDS transpose (row s = lo16, col = d within 32-step)
    #pragma unroll
    for (int i = 0; i < 2; ++i) {
      const f4 oi = i ? o1 : o0;
      const int dl = kh * 640 + c * 32 + i * 16 + hi4 * 4;
      f4 pbv = *(const f4*)&pbs[dl];
      f4 r;
      #pragma unroll
      for (int j = 0; j < 4; ++j) r[j] = oi[j] + pbv[j];
      *(f4*)&lds[w][lo16][i * 16 + hi4 * 4] = r;
    }
    // 2 stores: instr k covers 8 rows x 128B segments
    #pragma unroll
    for (int k = 0; k < 2; ++k) {
      const int rr = k * 8 + (lane >> 3);
      f4 v = *(const f4*)&lds[w][rr][(lane & 7) * 4];
      *(f4*)(outp + (size_t)rr * ND + c * 32 + (lane & 7) * 4) = v;
    }
  }
}

extern "C" void kernel_launch(void* const* d_in, const int* in_sizes, int n_in,
                              void* d_out, int out_size, void* d_ws, size_t ws_size,
                              hipStream_t stream) {
  const float* x      = (const float*)d_in[0];
  const float* embed  = (const float*)d_in[1];
  const float* w_down = (const float*)d_in[2];
  const float* b_down = (const float*)d_in[3];
  const float* w_up   = (const float*)d_in[4];
  const float* b_up   = (const float*)d_in[5];
  float* out = (float*)d_out;

  char* ws = (char*)d_ws;
  unsigned short* W2F  = (unsigned short*)ws;                // 1,310,720 B
  unsigned short* W3FB = (unsigned short*)(ws + 1310720);    // 1,310,720 B
  float* h2bias        = (float*)(ws + 2621440);             //     2,048 B
  uint4* h2F           = (uint4*)(ws + 2623488);             // 4,194,304 B

  prep_all<<<2721, 256, 0, stream>>>(embed, w_down, w_up, b_down, W2F, W3FB, h2bias);
  k1_h2   <<<1024, 256, 0, stream>>>(x, W2F, h2bias, h2F);
  k2_out  <<<1024, 256, 0, stream>>>(h2F, embed, b_up, W3FB, out);
}